// Round 4
// baseline (211.175 us; speedup 1.0000x reference)
//
#include <hip/hip_runtime.h>
#include <hip/hip_bf16.h>

// Problem constants (fixed by the reference file)
#define BATCH   8
#define NVERT   50000     // N
#define CIN     32
#define LSP     9
#define COUT    64
#define MVERT   12500
#define NNZ     37500

#define TILE_T  64        // tasks per block-tile
#define TPB     586       // ceil(NNZ/TILE_T)
#define NFRAG   2304      // 9 s * 4 quad * 64 (A-frags per block; B-frags total)
#define XELEMS  (BATCH * NVERT * CIN)   // 12,800,000
#define OUTDW   (BATCH * MVERT * COUT)  // 6,400,000 floats = 25.6 MB

#define PRE_BLOCKS  6250   // precast x: 256 thr * 8 floats = 2048 floats/block
#define PACK_BLOCKS 9      // pack W: 2304 frags
#define ZERO_BLOCKS 6250   // zero out: 256 thr * 4 dwords... (16B) = 4096 B/block

typedef __attribute__((ext_vector_type(8))) short  short8;   // 8 bf16 (4 VGPR)
typedef __attribute__((ext_vector_type(4))) float  floatx4;  // MFMA C/D

// fp32 -> bf16 round-to-nearest-even
static __device__ __forceinline__ unsigned short f2bf(float f) {
    union { float f; unsigned int u; } c; c.f = f;
    unsigned int u = c.u;
    return (unsigned short)((u + 0x7fffu + ((u >> 16) & 1u)) >> 16);
}

// async 16B global->LDS DMA; lds dest = wave-uniform base + lane*16
static __device__ __forceinline__ void dma16(const void* g, void* l) {
    typedef __attribute__((address_space(1))) const void gvoid;
    typedef __attribute__((address_space(3))) void lvoid;
    __builtin_amdgcn_global_load_lds(
        (gvoid*)(unsigned long long)g,
        (lvoid*)(unsigned int)(unsigned long long)l,   // generic LDS ptr: low 32 bits = LDS offset
        16, 0, 0);
}

// ---- prep: [0,PRE) precast x->bf16 ; [PRE,PRE+9) pack W frags ; rest zero out
__global__ __launch_bounds__(256)
void prep_kernel(const float* __restrict__ x, const float* __restrict__ w,
                 unsigned short* __restrict__ x16, unsigned short* __restrict__ wp,
                 float* __restrict__ out)
{
    const int blk = blockIdx.x;
    const int tid = threadIdx.x;
    if (blk < PRE_BLOCKS) {
        // 8 consecutive floats -> 8 bf16 (16 B store)
        const size_t base = ((size_t)blk * 256 + tid) * 8;
        const float4* s = (const float4*)(x + base);
        float4 a = s[0], c = s[1];
        unsigned short t[8];
        t[0]=f2bf(a.x); t[1]=f2bf(a.y); t[2]=f2bf(a.z); t[3]=f2bf(a.w);
        t[4]=f2bf(c.x); t[5]=f2bf(c.y); t[6]=f2bf(c.z); t[7]=f2bf(c.w);
        *(uint4*)(x16 + base) = *(uint4*)t;
    } else if (blk < PRE_BLOCKS + PACK_BLOCKS) {
        // B-frag f=(s*4+g)*64+lane holds W[s*32+(lane>>4)*8+j][g*16+(lane&15)]
        const int f = (blk - PRE_BLOCKS) * 256 + tid;
        if (f < NFRAG) {
            int s = f >> 8, g = (f >> 6) & 3, lane = f & 63;
            int k0 = s * 32 + (lane >> 4) * 8, col = g * 16 + (lane & 15);
            unsigned short t[8];
            #pragma unroll
            for (int j = 0; j < 8; ++j)
                t[j] = f2bf(w[(size_t)(k0 + j) * COUT + col]);
            ((uint4*)wp)[f] = *(uint4*)t;
        }
    } else {
        const size_t base = ((size_t)(blk - PRE_BLOCKS - PACK_BLOCKS) * 256 + tid) * 4;
        if (base < OUTDW) *(uint4*)(out + base) = (uint4){0, 0, 0, 0};
    }
}

__global__ __launch_bounds__(256)
void spiral_mfma2_kernel(const unsigned short* __restrict__ x16,
                         const unsigned short* __restrict__ wp,
                         const float* __restrict__ bias,
                         const float* __restrict__ vals,
                         const int* __restrict__ spiral,
                         const int* __restrict__ rows,
                         const int* __restrict__ cols,
                         float* __restrict__ out)
{
    // fragment-ordered: frag F=((s*4+quad)*64 + t), 16 B each -> 36,864 B, 4 blocks/CU
    __shared__ unsigned short sG[NFRAG * 8];

    const int bid  = blockIdx.x;
    const int b    = bid / TPB;
    const int tile = bid - b * TPB;
    const int z0   = tile * TILE_T;
    const int tcnt = min(TILE_T, NNZ - z0);
    const int tid  = threadIdx.x;
    const int w    = tid >> 6;     // wave 0..3
    const int lane = tid & 63;

    // ---- staging: wave w stages chunks i = 4j + w (s=j, quad=w), j=0..8
    // lane L's 16 B lands at chunk_base + L*16 and must hold task t=L's data
    int zc = z0 + lane; if (zc >= NNZ) zc = NNZ - 1;      // tail clamp; epilogue guards
    const int  c  = cols[zc];
    const int* sp = spiral + c * LSP;
    int idx[9];
    #pragma unroll
    for (int j = 0; j < 9; ++j) idx[j] = sp[j];

    const unsigned short* xb = x16 + (size_t)b * NVERT * CIN;
    #pragma unroll
    for (int j = 0; j < 9; ++j) {
        const unsigned short* src = xb + (size_t)idx[j] * CIN + w * 8;  // k = j*32 + w*8 ..+8
        dma16(src, sG + (size_t)(4 * j + w) * 512);                     // 512 shorts = 1 KB
    }
    __syncthreads();   // drains vmcnt incl. lds-DMA (m97 pattern)

    // ---- MFMA: wave w computes tasks [16w,16w+16) x 64 channels
    const int quad = lane >> 4;
    const int m16  = lane & 15;

    floatx4 acc[4];
    #pragma unroll
    for (int g = 0; g < 4; ++g) acc[g] = (floatx4){0.f, 0.f, 0.f, 0.f};

    #pragma unroll
    for (int s = 0; s < 9; ++s) {
        short8 af = *(const short8*)(sG + (size_t)((s * 4 + quad) * 64 + 16 * w + m16) * 8);
        #pragma unroll
        for (int g = 0; g < 4; ++g) {
            short8 bf = *(const short8*)(wp + (size_t)((s * 4 + g) * 64 + lane) * 8);
            acc[g] = __builtin_amdgcn_mfma_f32_16x16x32_bf16(af, bf, acc[g], 0, 0, 0);
        }
    }

    // ---- epilogue: bias + ELU + scale + scatter-add
    // C layout: ch_tile col = lane&15, task row = quad*4 + reg
    #pragma unroll
    for (int r = 0; r < 4; ++r) {
        int t = 16 * w + quad * 4 + r;
        if (t < tcnt) {
            int z   = z0 + t;
            float v = vals[z];
            int row = rows[z];
            float* dst = out + ((size_t)b * MVERT + row) * COUT;
            #pragma unroll
            for (int g = 0; g < 4; ++g) {
                int ch  = g * 16 + m16;
                float y = acc[g][r] + bias[ch];
                y = (y > 0.0f) ? y : (__expf(y) - 1.0f);
                atomicAdd(dst + ch, y * v);
            }
        }
    }
}

extern "C" void kernel_launch(void* const* d_in, const int* in_sizes, int n_in,
                              void* d_out, int out_size, void* d_ws, size_t ws_size,
                              hipStream_t stream) {
    const float* x      = (const float*)d_in[0];
    const float* w      = (const float*)d_in[1];
    const float* bias   = (const float*)d_in[2];
    const float* vals   = (const float*)d_in[3];
    const int*   spiral = (const int*)d_in[4];   // int32 per harness convention
    const int*   rows   = (const int*)d_in[5];
    const int*   cols   = (const int*)d_in[6];
    float* out = (float*)d_out;

    // workspace layout: wp (36,864 B) | x16 (25,600,000 B)
    unsigned short* wp  = (unsigned short*)d_ws;
    unsigned short* x16 = (unsigned short*)((char*)d_ws + (size_t)NFRAG * 16);

    const int prep_grid = PRE_BLOCKS + PACK_BLOCKS + ZERO_BLOCKS;
    prep_kernel<<<prep_grid, 256, 0, stream>>>(x, w, x16, wp, out);
    spiral_mfma2_kernel<<<BATCH * TPB, 256, 0, stream>>>(x16, wp, bias, vals,
                                                         spiral, rows, cols, out);
}

// Round 5
// 185.007 us; speedup vs baseline: 1.1414x; 1.1414x over previous
//
#include <hip/hip_runtime.h>

// Problem constants (fixed by the reference file)
#define BATCH   8
#define NVERT   50000
#define CIN     32
#define LSP     9
#define COUT    64
#define MVERT   12500
#define NNZ     37500

#define TILE_T  64
#define TPB     586            // ceil(NNZ/64); last tile has 60 tasks
#define NFRAG   2304           // 9 s * 4 g * 64 lanes (B fragments)
#define OUTDW   (BATCH * MVERT * COUT)   // 6,400,000 floats
#define XELEMS  (BATCH * NVERT * CIN)    // 12,800,000

#define PRE_BLOCKS  6250       // precast x -> bf16
#define PACK_BLOCKS 9          // pack W frags
#define ZERO_BLOCKS 6250       // zero out (16 B/thread)
#define HZ_BLOCKS   49         // zero histogram (1 int/thread)

typedef __attribute__((ext_vector_type(8))) short  short8;
typedef __attribute__((ext_vector_type(4))) float  floatx4;

static __device__ __forceinline__ unsigned short f2bf(float f) {
    union { float f; unsigned int u; } c; c.f = f;
    unsigned int u = c.u;
    return (unsigned short)((u + 0x7fffu + ((u >> 16) & 1u)) >> 16);
}

// async 16B global->LDS DMA; lds dest = wave-uniform base + lane*16
static __device__ __forceinline__ void dma16(const void* g, void* l) {
    typedef __attribute__((address_space(1))) const void gvoid;
    typedef __attribute__((address_space(3))) void lvoid;
    __builtin_amdgcn_global_load_lds(
        (gvoid*)(unsigned long long)g,
        (lvoid*)(unsigned int)(unsigned long long)l,
        16, 0, 0);
}

// ---- k1: precast x | pack W | zero out | zero hist
__global__ __launch_bounds__(256)
void prep_kernel(const float* __restrict__ x, const float* __restrict__ w,
                 unsigned short* __restrict__ x16, unsigned short* __restrict__ wp,
                 float* __restrict__ out, int* __restrict__ hist)
{
    const int blk = blockIdx.x;
    const int tid = threadIdx.x;
    if (blk < PRE_BLOCKS) {
        const size_t base = ((size_t)blk * 256 + tid) * 8;
        const float4* s = (const float4*)(x + base);
        float4 a = s[0], c = s[1];
        unsigned short t[8];
        t[0]=f2bf(a.x); t[1]=f2bf(a.y); t[2]=f2bf(a.z); t[3]=f2bf(a.w);
        t[4]=f2bf(c.x); t[5]=f2bf(c.y); t[6]=f2bf(c.z); t[7]=f2bf(c.w);
        *(uint4*)(x16 + base) = *(uint4*)t;
    } else if (blk < PRE_BLOCKS + PACK_BLOCKS) {
        // B-frag f=(s*4+g)*64+lane holds W[s*32+(lane>>4)*8+j][g*16+(lane&15)]
        const int f = (blk - PRE_BLOCKS) * 256 + tid;
        if (f < NFRAG) {
            int s = f >> 8, g = (f >> 6) & 3, lane = f & 63;
            int k0 = s * 32 + (lane >> 4) * 8, col = g * 16 + (lane & 15);
            unsigned short t[8];
            #pragma unroll
            for (int j = 0; j < 8; ++j)
                t[j] = f2bf(w[(size_t)(k0 + j) * COUT + col]);
            ((uint4*)wp)[f] = *(uint4*)t;
        }
    } else if (blk < PRE_BLOCKS + PACK_BLOCKS + ZERO_BLOCKS) {
        const size_t base = ((size_t)(blk - PRE_BLOCKS - PACK_BLOCKS) * 256 + tid) * 4;
        if (base < OUTDW) *(uint4*)(out + base) = (uint4){0, 0, 0, 0};
    } else {
        const int i = (blk - PRE_BLOCKS - PACK_BLOCKS - ZERO_BLOCKS) * 256 + tid;
        if (i < MVERT) hist[i] = 0;
    }
}

// ---- k2: histogram of rows
__global__ __launch_bounds__(256)
void hist_kernel(const int* __restrict__ rows, int* __restrict__ hist) {
    int z = blockIdx.x * 256 + threadIdx.x;
    if (z < NNZ) atomicAdd(&hist[rows[z]], 1);
}

// ---- k3: exclusive scan of hist -> off2 (single block)
__global__ __launch_bounds__(1024)
void scan_kernel(const int* __restrict__ hist, int* __restrict__ off2) {
    __shared__ int sh[1024];
    const int t = threadIdx.x;
    const int base = t * 13;                 // 13*1024 >= 12500
    int loc[13];
    int s = 0;
    #pragma unroll
    for (int j = 0; j < 13; ++j) {
        int i = base + j;
        int v = (i < MVERT) ? hist[i] : 0;
        loc[j] = s; s += v;
    }
    sh[t] = s;
    __syncthreads();
    for (int d = 1; d < 1024; d <<= 1) {
        int v = (t >= d) ? sh[t - d] : 0;
        __syncthreads();
        sh[t] += v;
        __syncthreads();
    }
    const int excl = sh[t] - s;
    #pragma unroll
    for (int j = 0; j < 13; ++j) {
        int i = base + j;
        if (i < MVERT) off2[i] = excl + loc[j];
    }
}

// ---- k4: scatter into row-sorted order
__global__ __launch_bounds__(256)
void scatter_kernel(const int* __restrict__ rows, const int* __restrict__ cols,
                    const float* __restrict__ vals, int* __restrict__ off2,
                    int* __restrict__ rows_s, int* __restrict__ cols_s,
                    float* __restrict__ vals_s) {
    int z = blockIdx.x * 256 + threadIdx.x;
    if (z < NNZ) {
        int r = rows[z];
        int pos = atomicAdd(&off2[r], 1);
        rows_s[pos] = r;
        cols_s[pos] = cols[z];
        vals_s[pos] = vals[z];
    }
}

// ---- k5: fused gather+GEMM+ELU+scale + run-aggregated scatter-add
// Barrier-free: each wave owns 16 sorted tasks and a private 9 KB LDS region.
__global__ __launch_bounds__(256)
void spiral_mfma3_kernel(const unsigned short* __restrict__ x16,
                         const unsigned short* __restrict__ wp,
                         const float* __restrict__ bias,
                         const int* __restrict__ spiral,
                         const int* __restrict__ rows_s,
                         const int* __restrict__ cols_s,
                         const float* __restrict__ vals_s,
                         float* __restrict__ out)
{
    __shared__ unsigned short sG[4 * 4608];   // 4 waves x 9216 B

    const int bid  = blockIdx.x;
    const int b    = bid / TPB;
    const int tile = bid - b * TPB;
    const int z0   = tile * TILE_T;
    const int tcnt = min(TILE_T, NNZ - z0);
    const int tid  = threadIdx.x;
    const int w    = tid >> 6;
    const int lane = tid & 63;
    const int quad = lane >> 4;
    const int m16  = lane & 15;
    const int z0w  = z0 + 16 * w;
    int nval = tcnt - 16 * w;
    nval = (nval < 0) ? 0 : ((nval > 16) ? 16 : nval);

    unsigned short* region = sG + w * 4608;   // 9216 B private to this wave

    // each 16-lane group carries the wave's 16 tasks (index m16)
    const int zc    = min(z0w + m16, NNZ - 1);
    const int c     = cols_s[zc];
    const int myrow = rows_s[zc];
    const int* sp   = spiral + c * LSP;

    // ---- stage: 9 DMAs; lane (quad,m16) fetches task m16, k=s*32+quad*8..+8
    // LDS layout: region + s*1024B + quad*256B + m16*16B == A-frag read order
    const unsigned short* xb = x16 + (size_t)b * NVERT * CIN;
    #pragma unroll
    for (int s = 0; s < 9; ++s) {
        int idx = sp[s];
        dma16(xb + (size_t)idx * CIN + quad * 8, region + s * 512);
    }
    asm volatile("s_waitcnt vmcnt(0)" ::: "memory");   // DMA has no dest reg: wait by hand

    // ---- MFMA: this wave's 16 tasks x 64 channels
    floatx4 acc[4];
    #pragma unroll
    for (int g = 0; g < 4; ++g) acc[g] = (floatx4){0.f, 0.f, 0.f, 0.f};

    #pragma unroll
    for (int s = 0; s < 9; ++s) {
        short8 af = *(const short8*)(region + s * 512 + quad * 128 + m16 * 8);
        #pragma unroll
        for (int g = 0; g < 4; ++g) {
            short8 bf = *(const short8*)(wp + (size_t)((s * 4 + g) * 64 + lane) * 8);
            acc[g] = __builtin_amdgcn_mfma_f32_16x16x32_bf16(af, bf, acc[g], 0, 0, 0);
        }
    }

    if (nval > 0) {
        // ---- bias + ELU + scale; stash task-vectors in own region [0,4096)
        float bs[4];
        #pragma unroll
        for (int g = 0; g < 4; ++g) bs[g] = bias[g * 16 + m16];
        float vr[4];
        #pragma unroll
        for (int r = 0; r < 4; ++r) vr[r] = vals_s[min(z0w + quad * 4 + r, NNZ - 1)];

        #pragma unroll
        for (int r = 0; r < 4; ++r) {
            const int tt = quad * 4 + r;   // task within wave (C row = quad*4+reg)
            #pragma unroll
            for (int g = 0; g < 4; ++g) {
                float y = acc[g][r] + bs[g];
                y = (y > 0.0f) ? y : (__expf(y) - 1.0f);
                *(float*)((char*)region + tt * 256 + (g * 16 + m16) * 4) = y * vr[r];
            }
        }

        // ---- run aggregation over sorted rows: lane = channel
        const int ch = lane;
        float a = 0.0f;
        int cur = __shfl(myrow, 0, 16);
        for (int t = 0; t < nval; ++t) {
            int rt = __shfl(myrow, t, 16);
            if (rt != cur) {
                atomicAdd(out + ((size_t)b * MVERT + cur) * COUT + ch, a);
                a = 0.0f; cur = rt;
            }
            a += *(const float*)((char*)region + t * 256 + ch * 4);
        }
        atomicAdd(out + ((size_t)b * MVERT + cur) * COUT + ch, a);
    }
}

extern "C" void kernel_launch(void* const* d_in, const int* in_sizes, int n_in,
                              void* d_out, int out_size, void* d_ws, size_t ws_size,
                              hipStream_t stream) {
    const float* x      = (const float*)d_in[0];
    const float* w      = (const float*)d_in[1];
    const float* bias   = (const float*)d_in[2];
    const float* vals   = (const float*)d_in[3];
    const int*   spiral = (const int*)d_in[4];
    const int*   rows   = (const int*)d_in[5];
    const int*   cols   = (const int*)d_in[6];
    float* out = (float*)d_out;

    // ws layout
    char* base = (char*)d_ws;
    unsigned short* wp     = (unsigned short*)(base);                    //    36,864 B
    unsigned short* x16    = (unsigned short*)(base + 36864);            // 25,600,000 B
    int*            hist   = (int*)(base + 25636864);                    //    50,000 B
    int*            off2   = (int*)(base + 25686864);                    //    50,000 B
    int*            rows_s = (int*)(base + 25736864);                    //   150,016 B
    int*            cols_s = (int*)(base + 25886880);                    //   150,016 B
    float*          vals_s = (float*)(base + 26036896);                  //   150,016 B

    const int prep_grid = PRE_BLOCKS + PACK_BLOCKS + ZERO_BLOCKS + HZ_BLOCKS;
    prep_kernel<<<prep_grid, 256, 0, stream>>>(x, w, x16, wp, out, hist);
    hist_kernel<<<147, 256, 0, stream>>>(rows, hist);
    scan_kernel<<<1, 1024, 0, stream>>>(hist, off2);
    scatter_kernel<<<147, 256, 0, stream>>>(rows, cols, vals, off2,
                                            rows_s, cols_s, vals_s);
    spiral_mfma3_kernel<<<BATCH * TPB, 256, 0, stream>>>(x16, wp, bias, spiral,
                                                         rows_s, cols_s, vals_s, out);
}

// Round 6
// 179.451 us; speedup vs baseline: 1.1768x; 1.0310x over previous
//
#include <hip/hip_runtime.h>

// Problem constants (fixed by the reference file)
#define BATCH   8
#define NVERT   50000
#define CIN     32
#define LSP     9
#define COUT    64
#define MVERT   12500
#define NNZ     37500

#define TILE_T  256            // tasks per block (64 per wave)
#define TPB     147            // ceil(NNZ/256); last tile has 124 valid tasks
#define NFRAG   2304           // 9 s * 4 g * 64 lanes (B fragments)
#define OUTDW   (BATCH * MVERT * COUT)   // 6,400,000 floats
#define XELEMS  (BATCH * NVERT * CIN)    // 12,800,000

#define PRE_BLOCKS  6250       // precast x -> bf16
#define PACK_BLOCKS 9          // pack W frags
#define ZERO_BLOCKS 6250       // zero out (16 B/thread)
#define HZ_BLOCKS   49         // zero histogram

typedef __attribute__((ext_vector_type(8))) short  short8;
typedef __attribute__((ext_vector_type(4))) float  floatx4;

static __device__ __forceinline__ unsigned short f2bf(float f) {
    union { float f; unsigned int u; } c; c.f = f;
    unsigned int u = c.u;
    return (unsigned short)((u + 0x7fffu + ((u >> 16) & 1u)) >> 16);
}

// ---- k1: precast x | pack W | zero out | zero hist
__global__ __launch_bounds__(256)
void prep_kernel(const float* __restrict__ x, const float* __restrict__ w,
                 unsigned short* __restrict__ x16, unsigned short* __restrict__ wp,
                 float* __restrict__ out, int* __restrict__ hist)
{
    const int blk = blockIdx.x;
    const int tid = threadIdx.x;
    if (blk < PRE_BLOCKS) {
        const size_t base = ((size_t)blk * 256 + tid) * 8;
        const float4* s = (const float4*)(x + base);
        float4 a = s[0], c = s[1];
        unsigned short t[8];
        t[0]=f2bf(a.x); t[1]=f2bf(a.y); t[2]=f2bf(a.z); t[3]=f2bf(a.w);
        t[4]=f2bf(c.x); t[5]=f2bf(c.y); t[6]=f2bf(c.z); t[7]=f2bf(c.w);
        *(uint4*)(x16 + base) = *(uint4*)t;
    } else if (blk < PRE_BLOCKS + PACK_BLOCKS) {
        // B-frag f=(s*4+g)*64+lane holds W[s*32+(lane>>4)*8+j][g*16+(lane&15)]
        const int f = (blk - PRE_BLOCKS) * 256 + tid;
        if (f < NFRAG) {
            int s = f >> 8, g = (f >> 6) & 3, lane = f & 63;
            int k0 = s * 32 + (lane >> 4) * 8, col = g * 16 + (lane & 15);
            unsigned short t[8];
            #pragma unroll
            for (int j = 0; j < 8; ++j)
                t[j] = f2bf(w[(size_t)(k0 + j) * COUT + col]);
            ((uint4*)wp)[f] = *(uint4*)t;
        }
    } else if (blk < PRE_BLOCKS + PACK_BLOCKS + ZERO_BLOCKS) {
        const size_t base = ((size_t)(blk - PRE_BLOCKS - PACK_BLOCKS) * 256 + tid) * 4;
        if (base < OUTDW) *(uint4*)(out + base) = (uint4){0, 0, 0, 0};
    } else {
        const int i = (blk - PRE_BLOCKS - PACK_BLOCKS - ZERO_BLOCKS) * 256 + tid;
        if (i < MVERT) hist[i] = 0;
    }
}

// ---- k2: histogram of rows
__global__ __launch_bounds__(256)
void hist_kernel(const int* __restrict__ rows, int* __restrict__ hist) {
    int z = blockIdx.x * 256 + threadIdx.x;
    if (z < NNZ) atomicAdd(&hist[rows[z]], 1);
}

// ---- k3: exclusive scan of hist -> off2 (single block)
__global__ __launch_bounds__(1024)
void scan_kernel(const int* __restrict__ hist, int* __restrict__ off2) {
    __shared__ int sh[1024];
    const int t = threadIdx.x;
    const int base = t * 13;
    int loc[13];
    int s = 0;
    #pragma unroll
    for (int j = 0; j < 13; ++j) {
        int i = base + j;
        int v = (i < MVERT) ? hist[i] : 0;
        loc[j] = s; s += v;
    }
    sh[t] = s;
    __syncthreads();
    for (int d = 1; d < 1024; d <<= 1) {
        int v = (t >= d) ? sh[t - d] : 0;
        __syncthreads();
        sh[t] += v;
        __syncthreads();
    }
    const int excl = sh[t] - s;
    #pragma unroll
    for (int j = 0; j < 13; ++j) {
        int i = base + j;
        if (i < MVERT) off2[i] = excl + loc[j];
    }
}

// ---- k4: scatter into row-sorted order
__global__ __launch_bounds__(256)
void scatter_kernel(const int* __restrict__ rows, const int* __restrict__ cols,
                    const float* __restrict__ vals, int* __restrict__ off2,
                    int* __restrict__ rows_s, int* __restrict__ cols_s,
                    float* __restrict__ vals_s) {
    int z = blockIdx.x * 256 + threadIdx.x;
    if (z < NNZ) {
        int r = rows[z];
        int pos = atomicAdd(&off2[r], 1);
        rows_s[pos] = r;
        cols_s[pos] = cols[z];
        vals_s[pos] = vals[z];
    }
}

// ---- k5: fused gather+GEMM+ELU+scale + run-aggregated scatter-add
// 64 tasks per wave (4 M-tiles share each B-fragment load). A-frags go
// global->VGPR directly (a lane's fragment IS 16 contiguous bytes of x16).
// No staging LDS, no barriers; 4 KB+pad LDS per wave only for the epilogue
// transpose (stride 68 floats -> <=2-way banks, free on CDNA4).
__global__ __launch_bounds__(256)
void spiral_mfma4_kernel(const unsigned short* __restrict__ x16,
                         const unsigned short* __restrict__ wp,
                         const float* __restrict__ bias,
                         const int* __restrict__ spiral,
                         const int* __restrict__ rows_s,
                         const int* __restrict__ cols_s,
                         const float* __restrict__ vals_s,
                         float* __restrict__ out)
{
    __shared__ float sS[4 * 16 * 68];   // 4 waves * 4352 B = 17,408 B

    const int bid  = blockIdx.x;
    const int b    = bid & 7;          // XCD swizzle: batch <-> XCD (x16/out slices L2-local)
    const int tile = bid >> 3;         // 0..146
    const int tid  = threadIdx.x;
    const int w    = tid >> 6;
    const int lane = tid & 63;
    const int quad = lane >> 4;
    const int m16  = lane & 15;
    const int z0w  = tile * TILE_T + 64 * w;   // this wave's first sorted-nnz index

    // per-lane task metadata: lane L carries task z0w+L (coalesced loads)
    const int   zc   = min(z0w + lane, NNZ - 1);
    const int   colv = cols_s[zc];
    const int   rowv = rows_s[zc];
    const float valv = vals_s[zc];

    int idx[9];
    #pragma unroll
    for (int s = 0; s < 9; ++s) idx[s] = spiral[colv * LSP + s];

    const unsigned short* xb = x16 + (size_t)b * NVERT * CIN;

    floatx4 acc[4][4];
    #pragma unroll
    for (int mt = 0; mt < 4; ++mt)
        #pragma unroll
        for (int g = 0; g < 4; ++g) acc[mt][g] = (floatx4){0.f, 0.f, 0.f, 0.f};

    #pragma unroll
    for (int s = 0; s < 9; ++s) {
        short8 bf[4];
        #pragma unroll
        for (int g = 0; g < 4; ++g)
            bf[g] = *(const short8*)(wp + (size_t)((s * 4 + g) * 64 + lane) * 8);
        #pragma unroll
        for (int mt = 0; mt < 4; ++mt) {
            // A-frag: lane (quad,m16) needs task mt*16+m16's vertex, k=quad*8..+8
            int tix = __shfl(idx[s], mt * 16 + m16);
            short8 af = *(const short8*)(xb + (size_t)tix * CIN + quad * 8);
            #pragma unroll
            for (int g = 0; g < 4; ++g)
                acc[mt][g] = __builtin_amdgcn_mfma_f32_16x16x32_bf16(af, bf[g], acc[mt][g], 0, 0, 0);
        }
    }

    // ---- epilogue per M-tile: bias+ELU+scale -> LDS transpose -> run-aggregated atomics
    float* region = sS + w * (16 * 68);
    float bs[4];
    #pragma unroll
    for (int g = 0; g < 4; ++g) bs[g] = bias[g * 16 + m16];

    float* outb = out + (size_t)b * MVERT * COUT;

    #pragma unroll
    for (int mt = 0; mt < 4; ++mt) {
        const int zbase = z0w + mt * 16;
        int nval = NNZ - zbase;
        nval = (nval < 0) ? 0 : ((nval > 16) ? 16 : nval);
        if (nval <= 0) continue;   // wave-uniform

        // C layout: ch col = g*16+m16, task row = quad*4+reg
        #pragma unroll
        for (int r = 0; r < 4; ++r) {
            const int tt = quad * 4 + r;
            const float vv = __shfl(valv, mt * 16 + tt);
            #pragma unroll
            for (int g = 0; g < 4; ++g) {
                float y = acc[mt][g][r] + bs[g];
                y = (y > 0.0f) ? y : (__expf(y) - 1.0f);
                region[tt * 68 + g * 16 + m16] = y * vv;
            }
        }
        // wave-internal LDS dependency: compiler inserts lgkmcnt waits

        // run aggregation over sorted rows: lane = channel (64 wide)
        float a = 0.0f;
        int cur = __shfl(rowv, mt * 16);
        for (int t = 0; t < nval; ++t) {
            int rt = __shfl(rowv, mt * 16 + t);
            if (rt != cur) {
                atomicAdd(outb + (size_t)cur * COUT + lane, a);
                a = 0.0f; cur = rt;
            }
            a += region[t * 68 + lane];
        }
        atomicAdd(outb + (size_t)cur * COUT + lane, a);
    }
}

extern "C" void kernel_launch(void* const* d_in, const int* in_sizes, int n_in,
                              void* d_out, int out_size, void* d_ws, size_t ws_size,
                              hipStream_t stream) {
    const float* x      = (const float*)d_in[0];
    const float* w      = (const float*)d_in[1];
    const float* bias   = (const float*)d_in[2];
    const float* vals   = (const float*)d_in[3];
    const int*   spiral = (const int*)d_in[4];
    const int*   rows   = (const int*)d_in[5];
    const int*   cols   = (const int*)d_in[6];
    float* out = (float*)d_out;

    // ws layout
    char* base = (char*)d_ws;
    unsigned short* wp     = (unsigned short*)(base);                    //    36,864 B
    unsigned short* x16    = (unsigned short*)(base + 36864);            // 25,600,000 B
    int*            hist   = (int*)(base + 25636864);
    int*            off2   = (int*)(base + 25686864);
    int*            rows_s = (int*)(base + 25736864);
    int*            cols_s = (int*)(base + 25886880);
    float*          vals_s = (float*)(base + 26036896);

    const int prep_grid = PRE_BLOCKS + PACK_BLOCKS + ZERO_BLOCKS + HZ_BLOCKS;
    prep_kernel<<<prep_grid, 256, 0, stream>>>(x, w, x16, wp, out, hist);
    hist_kernel<<<147, 256, 0, stream>>>(rows, hist);
    scan_kernel<<<1, 1024, 0, stream>>>(hist, off2);
    scatter_kernel<<<147, 256, 0, stream>>>(rows, cols, vals, off2,
                                            rows_s, cols_s, vals_s);
    spiral_mfma4_kernel<<<BATCH * TPB, 256, 0, stream>>>(x16, wp, bias, spiral,
                                                         rows_s, cols_s, vals_s, out);
}